// Round 10
// baseline (348.488 us; speedup 1.0000x reference)
//
#include <hip/hip_runtime.h>
#include <math.h>

#define N_NODES 50000
#define N_GRAPHS 64
#define HID 128
#define SCAN_B 196  // ceil(50000/256)

typedef _Float16 half8 __attribute__((ext_vector_type(8)));
typedef float f32x4 __attribute__((ext_vector_type(4)));

__device__ __forceinline__ float lrelu(float e) { return e > 0.f ? e : 0.2f * e; }
__device__ __forceinline__ float elu_fast(float o) { return o > 0.f ? o : __expf(o) - 1.f; }

// ---------------- CSR count + (fused) weight prep ----------------
// blocks [0, nblk): edge counting + sentinel init; blocks [nblk, nblk+30): W pack / alpha fold
__global__ void count_prep(const int* __restrict__ dst, int n_e, int nblk,
                           int* __restrict__ counts, int* __restrict__ start,
                           const float* __restrict__ W0, const float* __restrict__ W1,
                           const float* __restrict__ W2,
                           const float* __restrict__ as0, const float* __restrict__ ad0,
                           const float* __restrict__ as1, const float* __restrict__ ad1,
                           const float* __restrict__ as2, const float* __restrict__ ad2,
                           _Float16* __restrict__ Wh0, _Float16* __restrict__ Wl0,
                           _Float16* __restrict__ Wh1, _Float16* __restrict__ Wl1,
                           _Float16* __restrict__ Wh2, _Float16* __restrict__ Wl2,
                           float* __restrict__ wfold) {
    int blk = blockIdx.x;
    if (blk < nblk) {
        if (blk == 0 && threadIdx.x <= N_GRAPHS) start[threadIdx.x] = -1;
        int e = blk * 256 + threadIdx.x;
        if (e < n_e) atomicAdd(&counts[dst[e]], 1);
        return;
    }
    int b = blk - nblk;  // 0..29
    if (b < 24) {
        int layer = b >> 3;
        const float* W = layer == 0 ? W0 : (layer == 1 ? W1 : W2);
        _Float16* Wh = layer == 0 ? Wh0 : (layer == 1 ? Wh1 : Wh2);
        _Float16* Wl = layer == 0 ? Wl0 : (layer == 1 ? Wl1 : Wl2);
        int t = (b & 7) * 256 + threadIdx.x;
        int lane = t & 63;
        int nt = (t >> 6) & 7;
        int kt = t >> 9;
        int n = nt * 16 + (lane & 15);
        int kbase = kt * 32 + (lane >> 4) * 8;
#pragma unroll
        for (int j = 0; j < 8; ++j) {
            float w = W[(size_t)(kbase + j) * 128 + n];
            _Float16 h = (_Float16)w;
            float r = w - (float)h;
            size_t idx = (size_t)t * 8 + j;
            Wh[idx] = h;
            Wl[idx] = (_Float16)r;
        }
    } else {
        int idx = b - 24;  // 0..5: layer*2 + which
        int layer = idx >> 1, which = idx & 1;
        const float* W = layer == 0 ? W0 : (layer == 1 ? W1 : W2);
        const float* a = which == 0 ? (layer == 0 ? as0 : (layer == 1 ? as1 : as2))
                                    : (layer == 0 ? ad0 : (layer == 1 ? ad1 : ad2));
        int k = threadIdx.x;
        if (k < 128) {
            float s = 0.f;
            for (int j = 0; j < 128; ++j) s = fmaf(W[k * 128 + j], a[j], s);
            wfold[idx * 128 + k] = s;
        }
    }
}

__global__ __launch_bounds__(256) void block_reduce(const int* __restrict__ counts,
                                                    int* __restrict__ bsum) {
    __shared__ int red[256];
    int t = threadIdx.x;
    int i = blockIdx.x * 256 + t;
    red[t] = (i < N_NODES) ? counts[i] : 0;
    __syncthreads();
#pragma unroll
    for (int off = 128; off; off >>= 1) {
        if (t < off) red[t] += red[t + off];
        __syncthreads();
    }
    if (t == 0) bsum[blockIdx.x] = red[0];
}

// fused: per-block redundant scan of bsum (196 entries) + local scan + boundary detection
__global__ __launch_bounds__(256) void block_scan(const int* __restrict__ counts,
                                                  const int* __restrict__ bsum,
                                                  const int* __restrict__ batch,
                                                  int* __restrict__ offs,
                                                  int* __restrict__ cursor,
                                                  int* __restrict__ start) {
    __shared__ int sb[256];
    __shared__ int sh[256];
    int t = threadIdx.x;
    int v = (t < SCAN_B) ? bsum[t] : 0;
    sb[t] = v;
    __syncthreads();
#pragma unroll
    for (int off = 1; off < 256; off <<= 1) {
        int u = (t >= off) ? sb[t - off] : 0;
        __syncthreads();
        sb[t] += u;
        __syncthreads();
    }
    int bpre = (blockIdx.x == 0) ? 0 : sb[blockIdx.x - 1];
    if (blockIdx.x == 0 && t == SCAN_B - 1) offs[N_NODES] = sb[t];

    int i = blockIdx.x * 256 + t;
    int c = (i < N_NODES) ? counts[i] : 0;
    sh[t] = c;
    __syncthreads();
#pragma unroll
    for (int off = 1; off < 256; off <<= 1) {
        int u = (t >= off) ? sh[t - off] : 0;
        __syncthreads();
        sh[t] += u;
        __syncthreads();
    }
    if (i < N_NODES) {
        int e = bpre + sh[t] - c;
        offs[i] = e;
        cursor[i] = e;
        int b = batch[i];
        if (i == 0) start[b] = 0;
        else if (batch[i - 1] != b) start[b] = i;
    }
}

// + fused d_out zeroing (pool accumulates into d_out later in the stream)
__global__ void scatter_kernel(const int* __restrict__ src, const int* __restrict__ dst, int n_e,
                               int* __restrict__ cursor, int* __restrict__ csr_src,
                               float* __restrict__ outz) {
    int gid = blockIdx.x * blockDim.x + threadIdx.x;
    if (gid < N_GRAPHS * HID) outz[gid] = 0.f;
    if (gid >= n_e) return;
    int d = dst[gid];
    int pos = atomicAdd(&cursor[d], 1);
    csr_src[pos] = src[gid];
}

// ---------------- MFMA GEMM: H16 = fp16(X)@W (2-term); exact fp32 alphas in-loop ----------------
__global__ __launch_bounds__(256) void gemm_mfma(const float* __restrict__ X,
                                                 const _Float16* __restrict__ Wh,
                                                 const _Float16* __restrict__ Wl,
                                                 const float* __restrict__ wsv,
                                                 const float* __restrict__ wdv,
                                                 _Float16* __restrict__ H16,
                                                 float* __restrict__ AS,
                                                 float* __restrict__ AD) {
    __shared__ float wsL[128], wdL[128];
    int t = threadIdx.x;
    if (t < 128) wsL[t] = wsv[t];
    else if (t < 256) wdL[t - 128] = wdv[t - 128];
    __syncthreads();

    int wave = t >> 6, lane = t & 63;
    int m15 = lane & 15, quad = lane >> 4;
    int rowbase = blockIdx.x * 64 + wave * 16;
    int arow = rowbase + m15;
    bool arow_ok = arow < N_NODES;

    f32x4 acc[8];
#pragma unroll
    for (int nt = 0; nt < 8; ++nt) acc[nt] = (f32x4){0.f, 0.f, 0.f, 0.f};
    float as_p = 0.f, ad_p = 0.f;

    const float* xrow = X + (size_t)arow * 128 + quad * 8;
#pragma unroll
    for (int kt = 0; kt < 4; ++kt) {
        f32x4 a0 = (f32x4){0.f, 0.f, 0.f, 0.f};
        f32x4 a1 = (f32x4){0.f, 0.f, 0.f, 0.f};
        if (arow_ok) {
            a0 = *(const f32x4*)(xrow + kt * 32);
            a1 = *(const f32x4*)(xrow + kt * 32 + 4);
        }
        int kb = kt * 32 + quad * 8;
        half8 ah;
#pragma unroll
        for (int j = 0; j < 4; ++j) {
            as_p = fmaf(a0[j], wsL[kb + j], as_p);
            ad_p = fmaf(a0[j], wdL[kb + j], ad_p);
            as_p = fmaf(a1[j], wsL[kb + 4 + j], as_p);
            ad_p = fmaf(a1[j], wdL[kb + 4 + j], ad_p);
            ah[j] = (_Float16)a0[j];
            ah[4 + j] = (_Float16)a1[j];
        }
#pragma unroll
        for (int nt = 0; nt < 8; ++nt) {
            size_t fidx = ((size_t)((kt * 8 + nt) * 64 + lane)) * 8;
            half8 bh = *(const half8*)(Wh + fidx);
            half8 bl = *(const half8*)(Wl + fidx);
            acc[nt] = __builtin_amdgcn_mfma_f32_16x16x32_f16(ah, bh, acc[nt], 0, 0, 0);
            acc[nt] = __builtin_amdgcn_mfma_f32_16x16x32_f16(ah, bl, acc[nt], 0, 0, 0);
        }
    }

#pragma unroll
    for (int nt = 0; nt < 8; ++nt) {
        int c = nt * 16 + m15;
#pragma unroll
        for (int reg = 0; reg < 4; ++reg) {
            int gr = rowbase + quad * 4 + reg;
            if (gr < N_NODES) H16[(size_t)gr * 128 + c] = (_Float16)acc[nt][reg];
        }
    }
    as_p += __shfl_xor(as_p, 16);
    ad_p += __shfl_xor(ad_p, 16);
    as_p += __shfl_xor(as_p, 32);
    ad_p += __shfl_xor(ad_p, 32);
    if (quad == 0 && arow_ok) { AS[arow] = as_p; AD[arow] = ad_p; }
}

// ---------------- fused softmax + fp16 gather: one wave per node ----------------
__global__ __launch_bounds__(256) void aggregate_kernel(const _Float16* __restrict__ H16,
                                                        const float* __restrict__ AS,
                                                        const float* __restrict__ AD,
                                                        const int* __restrict__ offs,
                                                        const int* __restrict__ csr_src,
                                                        const float* __restrict__ bias,
                                                        float* __restrict__ OUT) {
    __shared__ int2 sh_sp[4][64];
    int w = threadIdx.x >> 6, lane = threadIdx.x & 63;
    int node = blockIdx.x * 4 + w;
    bool valid = node < N_NODES;

    int beg = 0, deg = 0;
    float ad = 0.f, eself = 0.f;
    if (valid) {
        beg = offs[node];
        deg = offs[node + 1] - beg;
        ad = AD[node];
        eself = lrelu(AS[node] + ad);
    }
    bool fast = deg <= 64;
    float m = 0.f, inv = 1.f, ps = 0.f;

    if (valid) {
        if (fast) {
            int s = 0;
            float ev = -INFINITY;
            if (lane < deg) {
                s = csr_src[beg + lane];
                ev = lrelu(AS[s] + ad);
            }
            m = ev;
#pragma unroll
            for (int off = 32; off; off >>= 1) m = fmaxf(m, __shfl_xor(m, off));
            m = fmaxf(m, eself);
            float p = (lane < deg) ? __expf(ev - m) : 0.f;
            float ssum = p;
#pragma unroll
            for (int off = 32; off; off >>= 1) ssum += __shfl_xor(ssum, off);
            ps = __expf(eself - m);
            inv = __builtin_amdgcn_rcpf(ssum + ps + 1e-16f);
            ps *= inv;
            float pc = p * inv;
            sh_sp[w][lane] = make_int2(s, __float_as_int(pc));
        } else {
            float mym = -INFINITY;
            for (int i = beg + lane; i < beg + deg; i += 64)
                mym = fmaxf(mym, lrelu(AS[csr_src[i]] + ad));
#pragma unroll
            for (int off = 32; off; off >>= 1) mym = fmaxf(mym, __shfl_xor(mym, off));
            m = fmaxf(mym, eself);
            float ssum = 0.f;
            for (int i = beg + lane; i < beg + deg; i += 64)
                ssum += __expf(lrelu(AS[csr_src[i]] + ad) - m);
#pragma unroll
            for (int off = 32; off; off >>= 1) ssum += __shfl_xor(ssum, off);
            ps = __expf(eself - m);
            inv = __builtin_amdgcn_rcpf(ssum + ps + 1e-16f);
            ps *= inv;
        }
    }
    __syncthreads();

    int q = lane >> 4, l16 = lane & 15;
    const half8* H8 = (const half8*)H16;  // row = 16 half8
    float accA[8] = {0.f, 0.f, 0.f, 0.f, 0.f, 0.f, 0.f, 0.f};
    float accB[8] = {0.f, 0.f, 0.f, 0.f, 0.f, 0.f, 0.f, 0.f};

    if (valid) {
        if (fast) {
            int k = q;
            for (; k + 4 < deg; k += 8) {
                int2 sp0 = sh_sp[w][k];
                int2 sp1 = sh_sp[w][k + 4];
                float c0 = __int_as_float(sp0.y);
                float c1 = __int_as_float(sp1.y);
                half8 h0 = H8[(size_t)sp0.x * 16 + l16];
                half8 h1 = H8[(size_t)sp1.x * 16 + l16];
#pragma unroll
                for (int i = 0; i < 8; ++i) {
                    accA[i] = fmaf(c0, (float)h0[i], accA[i]);
                    accB[i] = fmaf(c1, (float)h1[i], accB[i]);
                }
            }
            if (k < deg) {
                int2 sp0 = sh_sp[w][k];
                float c0 = __int_as_float(sp0.y);
                half8 h0 = H8[(size_t)sp0.x * 16 + l16];
#pragma unroll
                for (int i = 0; i < 8; ++i) accA[i] = fmaf(c0, (float)h0[i], accA[i]);
            }
        } else {
            for (int k = q; k < deg; k += 4) {
                int s = csr_src[beg + k];
                float c = __expf(lrelu(AS[s] + ad) - m) * inv;
                half8 h0 = H8[(size_t)s * 16 + l16];
#pragma unroll
                for (int i = 0; i < 8; ++i) accA[i] = fmaf(c, (float)h0[i], accA[i]);
            }
        }
    }

#pragma unroll
    for (int i = 0; i < 8; ++i) {
        accA[i] += accB[i];
        accA[i] += __shfl_xor(accA[i], 16);
        accA[i] += __shfl_xor(accA[i], 32);
    }

    // epilogue split across quads 0 and 1 (each stores one f32x4)
    if (valid && q < 2) {
        half8 hs = H8[(size_t)node * 16 + l16];
        int base = q * 4;
        f32x4 b4 = ((const f32x4*)bias)[l16 * 2 + q];
        f32x4 o;
        o.x = fmaf(ps, (float)hs[base + 0], accA[base + 0]) + b4.x;
        o.y = fmaf(ps, (float)hs[base + 1], accA[base + 1]) + b4.y;
        o.z = fmaf(ps, (float)hs[base + 2], accA[base + 2]) + b4.z;
        o.w = fmaf(ps, (float)hs[base + 3], accA[base + 3]) + b4.w;
        o.x = elu_fast(o.x);
        o.y = elu_fast(o.y);
        o.z = elu_fast(o.z);
        o.w = elu_fast(o.w);
        ((f32x4*)OUT)[(size_t)node * 32 + l16 * 2 + q] = o;
    }
}

// ---------------- single-dispatch pool: pre-divided atomic accumulate ----------------
__device__ __forceinline__ int estart(const int* __restrict__ start, int g) {
    for (; g < N_GRAPHS; ++g) {
        int v = start[g];
        if (v >= 0) return v;
    }
    return N_NODES;
}

__global__ __launch_bounds__(128) void pool_kernel(const float* __restrict__ F,
                                                   const int* __restrict__ start,
                                                   float* __restrict__ out) {
    int b = blockIdx.x;
    int g = b >> 4, sub = b & 15;
    int c = threadIdx.x;
    int s0 = estart(start, g), e0 = estart(start, g + 1);
    float acc = 0.f;
    for (int i = s0 + sub; i < e0; i += 16) acc += F[(size_t)i * 128 + c];
    int cnt = e0 - s0;
    float r = 1.f / (float)(cnt > 1 ? cnt : 1);
    atomicAdd(&out[(size_t)g * 128 + c], acc * r);
}

extern "C" void kernel_launch(void* const* d_in, const int* in_sizes, int n_in,
                              void* d_out, int out_size, void* d_ws, size_t ws_size,
                              hipStream_t stream) {
    const float* x = (const float*)d_in[0];
    const int* edge_index = (const int*)d_in[1];
    const int* batch = (const int*)d_in[2];
    const float* W[3]   = {(const float*)d_in[3], (const float*)d_in[7], (const float*)d_in[11]};
    const float* avs[3] = {(const float*)d_in[4], (const float*)d_in[8], (const float*)d_in[12]};
    const float* avd[3] = {(const float*)d_in[5], (const float*)d_in[9], (const float*)d_in[13]};
    const float* bb[3]  = {(const float*)d_in[6], (const float*)d_in[10], (const float*)d_in[14]};
    int E0 = in_sizes[1] / 2;
    const int* esrc = edge_index;
    const int* edst = edge_index + E0;

    char* p = (char*)d_ws;
    auto alloc = [&](size_t bytes) -> void* {
        void* q = (void*)p;
        p += (bytes + 255) & ~(size_t)255;
        return q;
    };
    int* counts   = (int*)alloc((size_t)N_NODES * 4);
    int* offs     = (int*)alloc((size_t)(N_NODES + 1) * 4);
    int* cursor   = (int*)alloc((size_t)N_NODES * 4);
    int* csr_src  = (int*)alloc((size_t)E0 * 4);
    int* start    = (int*)alloc((N_GRAPHS + 1) * 4);
    int* bsum     = (int*)alloc(SCAN_B * 4);
    float* AS     = (float*)alloc((size_t)N_NODES * 4);
    float* AD     = (float*)alloc((size_t)N_NODES * 4);
    float* wfold  = (float*)alloc(6 * 128 * 4);
    _Float16* H16 = (_Float16*)alloc((size_t)N_NODES * HID * 2);
    float* FA     = (float*)alloc((size_t)N_NODES * HID * 4);
    float* FB     = (float*)alloc((size_t)N_NODES * HID * 4);
    _Float16* Wh[3], *Wl[3];
    for (int l = 0; l < 3; ++l) {
        Wh[l] = (_Float16*)alloc(16384 * 2);
        Wl[l] = (_Float16*)alloc(16384 * 2);
    }

    // CSR build + boundaries + fused weight prep
    int nblk = (E0 + 255) / 256;
    hipMemsetAsync(counts, 0, (size_t)N_NODES * 4, stream);
    count_prep<<<nblk + 30, 256, 0, stream>>>(edst, E0, nblk, counts, start,
                                              W[0], W[1], W[2], avs[0], avd[0], avs[1], avd[1],
                                              avs[2], avd[2], Wh[0], Wl[0], Wh[1], Wl[1],
                                              Wh[2], Wl[2], wfold);
    block_reduce<<<SCAN_B, 256, 0, stream>>>(counts, bsum);
    block_scan<<<SCAN_B, 256, 0, stream>>>(counts, bsum, batch, offs, cursor, start);
    scatter_kernel<<<nblk, 256, 0, stream>>>(esrc, edst, E0, cursor, csr_src, (float*)d_out);

    // 3 GAT layers
    const float* cur = x;
    float* feat[2] = {FA, FB};
    for (int l = 0; l < 3; ++l) {
        gemm_mfma<<<(N_NODES + 63) / 64, 256, 0, stream>>>(cur, Wh[l], Wl[l],
                                                           wfold + (l * 2) * 128,
                                                           wfold + (l * 2 + 1) * 128,
                                                           H16, AS, AD);
        float* nxt = feat[l & 1];
        aggregate_kernel<<<(N_NODES + 3) / 4, 256, 0, stream>>>(H16, AS, AD, offs, csr_src,
                                                                bb[l], nxt);
        cur = nxt;
    }

    // single-dispatch pool (d_out zeroed in scatter_kernel)
    pool_kernel<<<N_GRAPHS * 16, 128, 0, stream>>>(cur, start, (float*)d_out);
}

// Round 11
// 335.768 us; speedup vs baseline: 1.0379x; 1.0379x over previous
//
#include <hip/hip_runtime.h>
#include <math.h>

#define N_NODES 50000
#define N_GRAPHS 64
#define HID 128
#define SCAN_B 196  // ceil(50000/256)

typedef _Float16 half8 __attribute__((ext_vector_type(8)));
typedef float f32x4 __attribute__((ext_vector_type(4)));

__device__ __forceinline__ float lrelu(float e) { return e > 0.f ? e : 0.2f * e; }
__device__ __forceinline__ float elu_fast(float o) { return o > 0.f ? o : __expf(o) - 1.f; }

// ---------------- CSR count + (fused) weight prep ----------------
// blocks [0, nblk): edge counting + sentinel init; blocks [nblk, nblk+30): W pack / alpha fold
__global__ void count_prep(const int* __restrict__ dst, int n_e, int nblk,
                           int* __restrict__ counts, int* __restrict__ start,
                           const float* __restrict__ W0, const float* __restrict__ W1,
                           const float* __restrict__ W2,
                           const float* __restrict__ as0, const float* __restrict__ ad0,
                           const float* __restrict__ as1, const float* __restrict__ ad1,
                           const float* __restrict__ as2, const float* __restrict__ ad2,
                           _Float16* __restrict__ Wh0, _Float16* __restrict__ Wh1,
                           _Float16* __restrict__ Wh2,
                           float* __restrict__ wfold) {
    int blk = blockIdx.x;
    if (blk < nblk) {
        if (blk == 0 && threadIdx.x <= N_GRAPHS) start[threadIdx.x] = -1;
        int e = blk * 256 + threadIdx.x;
        if (e < n_e) atomicAdd(&counts[dst[e]], 1);
        return;
    }
    int b = blk - nblk;  // 0..29
    if (b < 24) {
        int layer = b >> 3;
        const float* W = layer == 0 ? W0 : (layer == 1 ? W1 : W2);
        _Float16* Wh = layer == 0 ? Wh0 : (layer == 1 ? Wh1 : Wh2);
        int t = (b & 7) * 256 + threadIdx.x;
        int lane = t & 63;
        int nt = (t >> 6) & 7;
        int kt = t >> 9;
        int n = nt * 16 + (lane & 15);
        int kbase = kt * 32 + (lane >> 4) * 8;
#pragma unroll
        for (int j = 0; j < 8; ++j) {
            float w = W[(size_t)(kbase + j) * 128 + n];
            Wh[(size_t)t * 8 + j] = (_Float16)w;
        }
    } else {
        int idx = b - 24;  // 0..5: layer*2 + which
        int layer = idx >> 1, which = idx & 1;
        const float* W = layer == 0 ? W0 : (layer == 1 ? W1 : W2);
        const float* a = which == 0 ? (layer == 0 ? as0 : (layer == 1 ? as1 : as2))
                                    : (layer == 0 ? ad0 : (layer == 1 ? ad1 : ad2));
        int k = threadIdx.x;
        if (k < 128) {
            float s = 0.f;
            for (int j = 0; j < 128; ++j) s = fmaf(W[k * 128 + j], a[j], s);
            wfold[idx * 128 + k] = s;
        }
    }
}

__global__ __launch_bounds__(256) void block_reduce(const int* __restrict__ counts,
                                                    int* __restrict__ bsum) {
    __shared__ int red[256];
    int t = threadIdx.x;
    int i = blockIdx.x * 256 + t;
    red[t] = (i < N_NODES) ? counts[i] : 0;
    __syncthreads();
#pragma unroll
    for (int off = 128; off; off >>= 1) {
        if (t < off) red[t] += red[t + off];
        __syncthreads();
    }
    if (t == 0) bsum[blockIdx.x] = red[0];
}

// fused: per-block redundant scan of bsum + local scan + boundary detection
__global__ __launch_bounds__(256) void block_scan(const int* __restrict__ counts,
                                                  const int* __restrict__ bsum,
                                                  const int* __restrict__ batch,
                                                  int* __restrict__ offs,
                                                  int* __restrict__ cursor,
                                                  int* __restrict__ start) {
    __shared__ int sb[256];
    __shared__ int sh[256];
    int t = threadIdx.x;
    int v = (t < SCAN_B) ? bsum[t] : 0;
    sb[t] = v;
    __syncthreads();
#pragma unroll
    for (int off = 1; off < 256; off <<= 1) {
        int u = (t >= off) ? sb[t - off] : 0;
        __syncthreads();
        sb[t] += u;
        __syncthreads();
    }
    int bpre = (blockIdx.x == 0) ? 0 : sb[blockIdx.x - 1];
    if (blockIdx.x == 0 && t == SCAN_B - 1) offs[N_NODES] = sb[t];

    int i = blockIdx.x * 256 + t;
    int c = (i < N_NODES) ? counts[i] : 0;
    sh[t] = c;
    __syncthreads();
#pragma unroll
    for (int off = 1; off < 256; off <<= 1) {
        int u = (t >= off) ? sh[t - off] : 0;
        __syncthreads();
        sh[t] += u;
        __syncthreads();
    }
    if (i < N_NODES) {
        int e = bpre + sh[t] - c;
        offs[i] = e;
        cursor[i] = e;
        int b = batch[i];
        if (i == 0) start[b] = 0;
        else if (batch[i - 1] != b) start[b] = i;
    }
}

// + fused d_out zeroing (pool accumulates into d_out later in the stream)
__global__ void scatter_kernel(const int* __restrict__ src, const int* __restrict__ dst, int n_e,
                               int* __restrict__ cursor, int* __restrict__ csr_src,
                               float* __restrict__ outz) {
    int gid = blockIdx.x * blockDim.x + threadIdx.x;
    if (gid < N_GRAPHS * HID) outz[gid] = 0.f;
    if (gid >= n_e) return;
    int d = dst[gid];
    int pos = atomicAdd(&cursor[d], 1);
    csr_src[pos] = src[gid];
}

// ---------------- MFMA GEMM: H16 = fp16(X)@fp16(W); exact fp32 alphas in-loop ----------------
// Single-term: W-rounding error (~2^-11 rel) is same order as the H16 storage rounding
// already present; alphas remain exact via wfold.
__global__ __launch_bounds__(256) void gemm_mfma(const float* __restrict__ X,
                                                 const _Float16* __restrict__ Wh,
                                                 const float* __restrict__ wsv,
                                                 const float* __restrict__ wdv,
                                                 _Float16* __restrict__ H16,
                                                 float* __restrict__ AS,
                                                 float* __restrict__ AD) {
    __shared__ float wsL[128], wdL[128];
    int t = threadIdx.x;
    if (t < 128) wsL[t] = wsv[t];
    else if (t < 256) wdL[t - 128] = wdv[t - 128];
    __syncthreads();

    int wave = t >> 6, lane = t & 63;
    int m15 = lane & 15, quad = lane >> 4;
    int rowbase = blockIdx.x * 64 + wave * 16;
    int arow = rowbase + m15;
    bool arow_ok = arow < N_NODES;

    f32x4 acc[8];
#pragma unroll
    for (int nt = 0; nt < 8; ++nt) acc[nt] = (f32x4){0.f, 0.f, 0.f, 0.f};
    float as_p = 0.f, ad_p = 0.f;

    const float* xrow = X + (size_t)arow * 128 + quad * 8;
#pragma unroll
    for (int kt = 0; kt < 4; ++kt) {
        f32x4 a0 = (f32x4){0.f, 0.f, 0.f, 0.f};
        f32x4 a1 = (f32x4){0.f, 0.f, 0.f, 0.f};
        if (arow_ok) {
            a0 = *(const f32x4*)(xrow + kt * 32);
            a1 = *(const f32x4*)(xrow + kt * 32 + 4);
        }
        int kb = kt * 32 + quad * 8;
        half8 ah;
#pragma unroll
        for (int j = 0; j < 4; ++j) {
            as_p = fmaf(a0[j], wsL[kb + j], as_p);
            ad_p = fmaf(a0[j], wdL[kb + j], ad_p);
            as_p = fmaf(a1[j], wsL[kb + 4 + j], as_p);
            ad_p = fmaf(a1[j], wdL[kb + 4 + j], ad_p);
            ah[j] = (_Float16)a0[j];
            ah[4 + j] = (_Float16)a1[j];
        }
#pragma unroll
        for (int nt = 0; nt < 8; ++nt) {
            size_t fidx = ((size_t)((kt * 8 + nt) * 64 + lane)) * 8;
            half8 bh = *(const half8*)(Wh + fidx);
            acc[nt] = __builtin_amdgcn_mfma_f32_16x16x32_f16(ah, bh, acc[nt], 0, 0, 0);
        }
    }

#pragma unroll
    for (int nt = 0; nt < 8; ++nt) {
        int c = nt * 16 + m15;
#pragma unroll
        for (int reg = 0; reg < 4; ++reg) {
            int gr = rowbase + quad * 4 + reg;
            if (gr < N_NODES) H16[(size_t)gr * 128 + c] = (_Float16)acc[nt][reg];
        }
    }
    as_p += __shfl_xor(as_p, 16);
    ad_p += __shfl_xor(ad_p, 16);
    as_p += __shfl_xor(as_p, 32);
    ad_p += __shfl_xor(ad_p, 32);
    if (quad == 0 && arow_ok) { AS[arow] = as_p; AD[arow] = ad_p; }
}

// ---------------- fused softmax + fp16 gather: one wave per node ----------------
__global__ __launch_bounds__(256) void aggregate_kernel(const _Float16* __restrict__ H16,
                                                        const float* __restrict__ AS,
                                                        const float* __restrict__ AD,
                                                        const int* __restrict__ offs,
                                                        const int* __restrict__ csr_src,
                                                        const float* __restrict__ bias,
                                                        float* __restrict__ OUT) {
    __shared__ int2 sh_sp[4][64];
    int w = threadIdx.x >> 6, lane = threadIdx.x & 63;
    int node = blockIdx.x * 4 + w;
    bool valid = node < N_NODES;

    int beg = 0, deg = 0;
    float ad = 0.f, eself = 0.f;
    if (valid) {
        beg = offs[node];
        deg = offs[node + 1] - beg;
        ad = AD[node];
        eself = lrelu(AS[node] + ad);
    }
    bool fast = deg <= 64;
    float m = 0.f, inv = 1.f, ps = 0.f;

    if (valid) {
        if (fast) {
            int s = 0;
            float ev = -INFINITY;
            if (lane < deg) {
                s = csr_src[beg + lane];
                ev = lrelu(AS[s] + ad);
            }
            m = ev;
#pragma unroll
            for (int off = 32; off; off >>= 1) m = fmaxf(m, __shfl_xor(m, off));
            m = fmaxf(m, eself);
            float p = (lane < deg) ? __expf(ev - m) : 0.f;
            float ssum = p;
#pragma unroll
            for (int off = 32; off; off >>= 1) ssum += __shfl_xor(ssum, off);
            ps = __expf(eself - m);
            inv = __builtin_amdgcn_rcpf(ssum + ps + 1e-16f);
            ps *= inv;
            float pc = p * inv;
            sh_sp[w][lane] = make_int2(s, __float_as_int(pc));
        } else {
            float mym = -INFINITY;
            for (int i = beg + lane; i < beg + deg; i += 64)
                mym = fmaxf(mym, lrelu(AS[csr_src[i]] + ad));
#pragma unroll
            for (int off = 32; off; off >>= 1) mym = fmaxf(mym, __shfl_xor(mym, off));
            m = fmaxf(mym, eself);
            float ssum = 0.f;
            for (int i = beg + lane; i < beg + deg; i += 64)
                ssum += __expf(lrelu(AS[csr_src[i]] + ad) - m);
#pragma unroll
            for (int off = 32; off; off >>= 1) ssum += __shfl_xor(ssum, off);
            ps = __expf(eself - m);
            inv = __builtin_amdgcn_rcpf(ssum + ps + 1e-16f);
            ps *= inv;
        }
    }
    __syncthreads();

    int q = lane >> 4, l16 = lane & 15;
    const half8* H8 = (const half8*)H16;  // row = 16 half8
    float accA[8] = {0.f, 0.f, 0.f, 0.f, 0.f, 0.f, 0.f, 0.f};
    float accB[8] = {0.f, 0.f, 0.f, 0.f, 0.f, 0.f, 0.f, 0.f};

    if (valid) {
        if (fast) {
            int k = q;
            for (; k + 4 < deg; k += 8) {
                int2 sp0 = sh_sp[w][k];
                int2 sp1 = sh_sp[w][k + 4];
                float c0 = __int_as_float(sp0.y);
                float c1 = __int_as_float(sp1.y);
                half8 h0 = H8[(size_t)sp0.x * 16 + l16];
                half8 h1 = H8[(size_t)sp1.x * 16 + l16];
#pragma unroll
                for (int i = 0; i < 8; ++i) {
                    accA[i] = fmaf(c0, (float)h0[i], accA[i]);
                    accB[i] = fmaf(c1, (float)h1[i], accB[i]);
                }
            }
            if (k < deg) {
                int2 sp0 = sh_sp[w][k];
                float c0 = __int_as_float(sp0.y);
                half8 h0 = H8[(size_t)sp0.x * 16 + l16];
#pragma unroll
                for (int i = 0; i < 8; ++i) accA[i] = fmaf(c0, (float)h0[i], accA[i]);
            }
        } else {
            for (int k = q; k < deg; k += 4) {
                int s = csr_src[beg + k];
                float c = __expf(lrelu(AS[s] + ad) - m) * inv;
                half8 h0 = H8[(size_t)s * 16 + l16];
#pragma unroll
                for (int i = 0; i < 8; ++i) accA[i] = fmaf(c, (float)h0[i], accA[i]);
            }
        }
    }

#pragma unroll
    for (int i = 0; i < 8; ++i) {
        accA[i] += accB[i];
        accA[i] += __shfl_xor(accA[i], 16);
        accA[i] += __shfl_xor(accA[i], 32);
    }

    if (valid && q < 2) {
        half8 hs = H8[(size_t)node * 16 + l16];
        int base = q * 4;
        f32x4 b4 = ((const f32x4*)bias)[l16 * 2 + q];
        f32x4 o;
        o.x = fmaf(ps, (float)hs[base + 0], accA[base + 0]) + b4.x;
        o.y = fmaf(ps, (float)hs[base + 1], accA[base + 1]) + b4.y;
        o.z = fmaf(ps, (float)hs[base + 2], accA[base + 2]) + b4.z;
        o.w = fmaf(ps, (float)hs[base + 3], accA[base + 3]) + b4.w;
        o.x = elu_fast(o.x);
        o.y = elu_fast(o.y);
        o.z = elu_fast(o.z);
        o.w = elu_fast(o.w);
        ((f32x4*)OUT)[(size_t)node * 32 + l16 * 2 + q] = o;
    }
}

// ---------------- single-dispatch pool: pre-divided atomic accumulate ----------------
__device__ __forceinline__ int estart(const int* __restrict__ start, int g) {
    for (; g < N_GRAPHS; ++g) {
        int v = start[g];
        if (v >= 0) return v;
    }
    return N_NODES;
}

__global__ __launch_bounds__(128) void pool_kernel(const float* __restrict__ F,
                                                   const int* __restrict__ start,
                                                   float* __restrict__ out) {
    int b = blockIdx.x;
    int g = b >> 4, sub = b & 15;
    int c = threadIdx.x;
    int s0 = estart(start, g), e0 = estart(start, g + 1);
    float acc = 0.f;
    for (int i = s0 + sub; i < e0; i += 16) acc += F[(size_t)i * 128 + c];
    int cnt = e0 - s0;
    float r = 1.f / (float)(cnt > 1 ? cnt : 1);
    atomicAdd(&out[(size_t)g * 128 + c], acc * r);
}

extern "C" void kernel_launch(void* const* d_in, const int* in_sizes, int n_in,
                              void* d_out, int out_size, void* d_ws, size_t ws_size,
                              hipStream_t stream) {
    const float* x = (const float*)d_in[0];
    const int* edge_index = (const int*)d_in[1];
    const int* batch = (const int*)d_in[2];
    const float* W[3]   = {(const float*)d_in[3], (const float*)d_in[7], (const float*)d_in[11]};
    const float* avs[3] = {(const float*)d_in[4], (const float*)d_in[8], (const float*)d_in[12]};
    const float* avd[3] = {(const float*)d_in[5], (const float*)d_in[9], (const float*)d_in[13]};
    const float* bb[3]  = {(const float*)d_in[6], (const float*)d_in[10], (const float*)d_in[14]};
    int E0 = in_sizes[1] / 2;
    const int* esrc = edge_index;
    const int* edst = edge_index + E0;

    char* p = (char*)d_ws;
    auto alloc = [&](size_t bytes) -> void* {
        void* q = (void*)p;
        p += (bytes + 255) & ~(size_t)255;
        return q;
    };
    int* counts   = (int*)alloc((size_t)N_NODES * 4);
    int* offs     = (int*)alloc((size_t)(N_NODES + 1) * 4);
    int* cursor   = (int*)alloc((size_t)N_NODES * 4);
    int* csr_src  = (int*)alloc((size_t)E0 * 4);
    int* start    = (int*)alloc((N_GRAPHS + 1) * 4);
    int* bsum     = (int*)alloc(SCAN_B * 4);
    float* AS     = (float*)alloc((size_t)N_NODES * 4);
    float* AD     = (float*)alloc((size_t)N_NODES * 4);
    float* wfold  = (float*)alloc(6 * 128 * 4);
    _Float16* H16 = (_Float16*)alloc((size_t)N_NODES * HID * 2);
    float* FA     = (float*)alloc((size_t)N_NODES * HID * 4);
    float* FB     = (float*)alloc((size_t)N_NODES * HID * 4);
    _Float16* Wh[3];
    for (int l = 0; l < 3; ++l) Wh[l] = (_Float16*)alloc(16384 * 2);

    // CSR build + boundaries + fused weight prep
    int nblk = (E0 + 255) / 256;
    hipMemsetAsync(counts, 0, (size_t)N_NODES * 4, stream);
    count_prep<<<nblk + 30, 256, 0, stream>>>(edst, E0, nblk, counts, start,
                                              W[0], W[1], W[2], avs[0], avd[0], avs[1], avd[1],
                                              avs[2], avd[2], Wh[0], Wh[1], Wh[2], wfold);
    block_reduce<<<SCAN_B, 256, 0, stream>>>(counts, bsum);
    block_scan<<<SCAN_B, 256, 0, stream>>>(counts, bsum, batch, offs, cursor, start);
    scatter_kernel<<<nblk, 256, 0, stream>>>(esrc, edst, E0, cursor, csr_src, (float*)d_out);

    // 3 GAT layers
    const float* cur = x;
    float* feat[2] = {FA, FB};
    for (int l = 0; l < 3; ++l) {
        gemm_mfma<<<(N_NODES + 63) / 64, 256, 0, stream>>>(cur, Wh[l],
                                                           wfold + (l * 2) * 128,
                                                           wfold + (l * 2 + 1) * 128,
                                                           H16, AS, AD);
        float* nxt = feat[l & 1];
        aggregate_kernel<<<(N_NODES + 3) / 4, 256, 0, stream>>>(H16, AS, AD, offs, csr_src,
                                                                bb[l], nxt);
        cur = nxt;
    }

    // single-dispatch pool (d_out zeroed in scatter_kernel)
    pool_kernel<<<N_GRAPHS * 16, 128, 0, stream>>>(cur, start, (float*)d_out);
}